// Round 16
// baseline (721.260 us; speedup 1.0000x reference)
//
#include <hip/hip_runtime.h>
#include <hip/hip_bf16.h>

// MultiLoRALinear: out = x@W.T + bias + (x @ A[idx]) @ B[idx]
// M=16384, K=4096, N=4096, rank 16.
//
// R16 = R15 (BK=64 dbuf-2, counted lgkm, 1 barrier/tile) with the inner
// fragment switched 16x16x32 -> 32x32x16 bf16.
// Rationale: 5 schedule variants all pin at MfmaUtil 47% = LDS+MFMA walls in
// series; scheduling saturated. 32x32x16 lowers the MFMA wall (m06/m119:
// 2382-2495 TF vs 2075-2176) and halves MFMA instruction count (issue slots).
// A/B frag: lane row=l&31, k=(l>>5)*8+j; C/D: col=lane&31,
// row=(r&3)+8*(r>>2)+4*(lane>>5) [m74/m101-verified].
// Swizzle: phys_slot = ((kk<<1)|h) ^ (row&7) applied as (base+mi*4096)^(kk<<5);
// 8 lanes per 4-bank group, balanced -> 0 conflicts expected.

#define M_TOT 16384
#define K_TOT 4096
#define N_TOT 4096
#define RANK 16
#define NT2 64   // K_TOT / 64

typedef __attribute__((ext_vector_type(8))) short bf16x8;
typedef __attribute__((ext_vector_type(4))) float f32x4;
typedef __attribute__((ext_vector_type(16))) float f32x16;

// ---------------- fp32 -> bf16 (round-to-nearest-even) ----------------
__device__ __forceinline__ unsigned short f2bf(float f) {
  unsigned int u = __builtin_bit_cast(unsigned int, f);
  u += 0x7fffu + ((u >> 16) & 1u);
  return (unsigned short)(u >> 16);
}

__global__ void cvt_bf16_kernel(const float* __restrict__ src,
                                unsigned short* __restrict__ dst, int n4) {
  int i = blockIdx.x * blockDim.x + threadIdx.x;
  const int stride = gridDim.x * blockDim.x;
  for (; i < n4; i += stride) {
    const float4 v = reinterpret_cast<const float4*>(src)[i];
    ushort4 o;
    o.x = f2bf(v.x); o.y = f2bf(v.y); o.z = f2bf(v.z); o.w = f2bf(v.w);
    reinterpret_cast<ushort4*>(dst)[i] = o;
  }
}

// ------------- inter = x @ A[slot] via MFMA (wave: 16 rows x r16) -------------
__global__ __launch_bounds__(256) void lora_inter_mfma_kernel(
    const unsigned short* __restrict__ xb,
    const float* __restrict__ loraA,
    const int* __restrict__ idx,
    float* __restrict__ inter) {
  const int lane = threadIdx.x & 63;
  const int wv = threadIdx.x >> 6;
  const int m0 = blockIdx.x * 64 + wv * 16;
  const int slot = idx[m0 >> 11];
  const int q = lane >> 4;
  const int c = lane & 15;
  const unsigned short* __restrict__ xrow = xb + (size_t)(m0 + c) * K_TOT + q * 8;
  const float* __restrict__ Abase = loraA + (size_t)slot * K_TOT * RANK + c;

  f32x4 acc = (f32x4){0.f, 0.f, 0.f, 0.f};
#pragma unroll 4
  for (int kt = 0; kt < K_TOT; kt += 32) {
    const bf16x8 af = *reinterpret_cast<const bf16x8*>(xrow + kt);
    const float* __restrict__ Ak = Abase + (size_t)(kt + q * 8) * RANK;
    bf16x8 bfr;
#pragma unroll
    for (int j = 0; j < 8; ++j) bfr[j] = (short)f2bf(Ak[(size_t)j * RANK]);
    acc = __builtin_amdgcn_mfma_f32_16x16x32_bf16(af, bfr, acc, 0, 0, 0);
  }
#pragma unroll
  for (int i = 0; i < 4; ++i)
    inter[(size_t)(m0 + q * 4 + i) * RANK + c] = acc[i];
}

// ---------------- BK=64 dbuf-2 256x256 GEMM, 8 waves, 32x32x16 ----------------
__device__ __forceinline__ void gload16(const void* g, void* l) {
  __builtin_amdgcn_global_load_lds(
      (const __attribute__((address_space(1))) unsigned int*)g,
      (__attribute__((address_space(3))) unsigned int*)l, 16, 0, 0);
}

#define GBARRIER() asm volatile("s_barrier" ::: "memory")
#define RD(p) (*reinterpret_cast<const bf16x8*>(p))

__global__ __launch_bounds__(512, 2) void gemm_fused_kernel(
    const unsigned short* __restrict__ xb,   // [M][K] bf16
    const unsigned short* __restrict__ wb,   // [N][K] bf16
    const float* __restrict__ bias,          // [N]
    const float* __restrict__ inter,         // [M][RANK] f32
    const float* __restrict__ loraB,         // [32][RANK][N] f32
    const int* __restrict__ idx,             // [8]
    float* __restrict__ out) {               // [M][N] f32
  // dbuf-2 x (A: 256x64 bf16 = 32KB @0, B: 32KB @32768) = 128 KiB
  __shared__ unsigned short lds[2][32768];
  char* ldsB = (char*)&lds[0][0];

  const int tid = threadIdx.x;
  const int lane = tid & 63;
  const int wv = tid >> 6;   // 0..7
  const int wr = wv >> 2;    // 0..1 (M half)
  const int wc = wv & 3;     // 0..3 (N quarter)

  // XCD-aware bijective swizzle: 1024 wgs, 8 XCDs, 128 per chunk
  const int bid = ((blockIdx.x & 7) << 7) | (blockIdx.x >> 3);
  const int m0 = (bid >> 4) << 8;   // 64 M-panels
  const int n0 = (bid & 15) << 8;   // 16 N-panels

  // ---- staging source (pre-permuted by the swizzle involution) ----
  const int r0 = tid >> 3;                              // 0..63
  const int scol = ((tid & 7) ^ (r0 & 7)) << 3;         // bf16 elems
  const unsigned short* xsrc = xb + (size_t)(m0 + r0) * K_TOT + scol;
  const unsigned short* wsrc = wb + (size_t)(n0 + r0) * K_TOT + scol;
  const int stg = tid << 4;

#define STAGE64(t)                                                       \
  do {                                                                   \
    const int _bo = (((t) & 1) << 16);                                   \
    const size_t _ko = (size_t)(t) * 64;                                 \
    gload16(xsrc + _ko,                        ldsB + _bo + stg);        \
    gload16(xsrc + (size_t)64  * K_TOT + _ko,  ldsB + _bo + 8192 + stg); \
    gload16(xsrc + (size_t)128 * K_TOT + _ko,  ldsB + _bo + 16384 + stg);\
    gload16(xsrc + (size_t)192 * K_TOT + _ko,  ldsB + _bo + 24576 + stg);\
    gload16(wsrc + _ko,                        ldsB + _bo + 32768 + stg);\
    gload16(wsrc + (size_t)64  * K_TOT + _ko,  ldsB + _bo + 40960 + stg);\
    gload16(wsrc + (size_t)128 * K_TOT + _ko,  ldsB + _bo + 49152 + stg);\
    gload16(wsrc + (size_t)192 * K_TOT + _ko,  ldsB + _bo + 57344 + stg);\
  } while (0)

  // ---- ds_read bases for 32x32 frags: row=l&31, logical slot=(kk<<1)|h ----
  // phys byte = row*128 + (((kk<<1)^h^c)<<4); apply kk as XOR (kk<<5).
  const int rowl = lane & 31;
  const int hc = (((lane >> 5) ^ (lane & 7)) << 4);
  const int abase = (wr * 128 + rowl) * 128 + hc;           // + mi*4096 ^ kk<<5
  const int bbase = 32768 + (wc * 64 + rowl) * 128 + hc;    // + ni*4096 ^ kk<<5

  f32x16 acc[4][2];
#pragma unroll
  for (int i = 0; i < 4; ++i)
#pragma unroll
    for (int j = 0; j < 2; ++j)
#pragma unroll
      for (int e = 0; e < 16; ++e) acc[i][j][e] = 0.f;

  // ---- prologue: stage tile 0, drain, barrier ----
  STAGE64(0);
  asm volatile("s_waitcnt vmcnt(0)" ::: "memory");
  GBARRIER();

#pragma unroll 1
  for (int t = 0; t < NT2; ++t) {
    const char* base = ldsB + ((t & 1) << 16);
    bf16x8 af[8], bf0[4], bf1[4];

    // cluster-1 reads (kk 0,1): B 4 + A 8; plus cluster-2 B reads (kk 2,3)
#pragma unroll
    for (int ni = 0; ni < 2; ++ni)
#pragma unroll
      for (int kk = 0; kk < 2; ++kk)
        bf0[ni * 2 + kk] = RD(base + ((bbase + ni * 4096) ^ (kk << 5)));
#pragma unroll
    for (int mi = 0; mi < 4; ++mi)
#pragma unroll
      for (int kk = 0; kk < 2; ++kk)
        af[mi * 2 + kk] = RD(base + ((abase + mi * 4096) ^ (kk << 5)));
#pragma unroll
    for (int ni = 0; ni < 2; ++ni)
#pragma unroll
      for (int kk = 0; kk < 2; ++kk)
        bf1[ni * 2 + kk] = RD(base + ((bbase + ni * 4096) ^ ((2 + kk) << 5)));
    if (t < NT2 - 1) STAGE64(t + 1);

    // wait cluster-1's 12 reads; bf1's 4 stay in flight under MFMA-1
    asm volatile("s_waitcnt lgkmcnt(4)" ::: "memory");
    __builtin_amdgcn_sched_barrier(0);
    __builtin_amdgcn_s_setprio(1);
#pragma unroll
    for (int mi = 0; mi < 4; ++mi)
#pragma unroll
      for (int ni = 0; ni < 2; ++ni)
#pragma unroll
        for (int kk = 0; kk < 2; ++kk)
          acc[mi][ni] = __builtin_amdgcn_mfma_f32_32x32x16_bf16(
              af[mi * 2 + kk], bf0[ni * 2 + kk], acc[mi][ni], 0, 0, 0);
    __builtin_amdgcn_s_setprio(0);
    __builtin_amdgcn_sched_barrier(0);  // pin: cluster-2 A reads stay below

    // cluster-2 A reads (kk 2,3), reuse af
#pragma unroll
    for (int mi = 0; mi < 4; ++mi)
#pragma unroll
      for (int kk = 0; kk < 2; ++kk)
        af[mi * 2 + kk] = RD(base + ((abase + mi * 4096) ^ ((2 + kk) << 5)));
    asm volatile("s_waitcnt lgkmcnt(0)" ::: "memory");
    __builtin_amdgcn_sched_barrier(0);
    __builtin_amdgcn_s_setprio(1);
#pragma unroll
    for (int mi = 0; mi < 4; ++mi)
#pragma unroll
      for (int ni = 0; ni < 2; ++ni)
#pragma unroll
        for (int kk = 0; kk < 2; ++kk)
          acc[mi][ni] = __builtin_amdgcn_mfma_f32_32x32x16_bf16(
              af[mi * 2 + kk], bf1[ni * 2 + kk], acc[mi][ni], 0, 0, 0);
    __builtin_amdgcn_s_setprio(0);
    __builtin_amdgcn_sched_barrier(0);

    // boundary: stage(t+1) resident for all waves
    asm volatile("s_waitcnt vmcnt(0)" ::: "memory");
    GBARRIER();
  }

  // ---- epilogue: out = acc + bias + inter @ B[slot] (32x32 C/D map) ----
  // col = lane&31; row = (r&3) + 8*(r>>2) + 4*(lane>>5)
  const int slot = idx[m0 >> 11];
  const float* __restrict__ Bmat = loraB + (size_t)slot * RANK * N_TOT;
  const int halfsel = (lane >> 5) << 2;
  const int gn0 = n0 + wc * 64 + rowl;

  float bcv[2][RANK];
  float bv[2];
#pragma unroll
  for (int ni = 0; ni < 2; ++ni) {
    const int gn = gn0 + ni * 32;
    bv[ni] = bias[gn];
#pragma unroll
    for (int p = 0; p < RANK; ++p) bcv[ni][p] = Bmat[(size_t)p * N_TOT + gn];
  }
#pragma unroll
  for (int mi = 0; mi < 4; ++mi) {
#pragma unroll
    for (int r = 0; r < 16; ++r) {
      const int gm = m0 + wr * 128 + mi * 32 + (r & 3) + 8 * (r >> 2) + halfsel;
      const float4* ivp = reinterpret_cast<const float4*>(inter + (size_t)gm * RANK);
      const float4 iv0 = ivp[0], iv1 = ivp[1], iv2 = ivp[2], iv3 = ivp[3];
      float* orow = out + (size_t)gm * N_TOT;
#pragma unroll
      for (int ni = 0; ni < 2; ++ni) {
        const float lora =
            iv0.x * bcv[ni][0]  + iv0.y * bcv[ni][1]  + iv0.z * bcv[ni][2]  + iv0.w * bcv[ni][3] +
            iv1.x * bcv[ni][4]  + iv1.y * bcv[ni][5]  + iv1.z * bcv[ni][6]  + iv1.w * bcv[ni][7] +
            iv2.x * bcv[ni][8]  + iv2.y * bcv[ni][9]  + iv2.z * bcv[ni][10] + iv2.w * bcv[ni][11] +
            iv3.x * bcv[ni][12] + iv3.y * bcv[ni][13] + iv3.z * bcv[ni][14] + iv3.w * bcv[ni][15];
        orow[gn0 + ni * 32] = acc[mi][ni][r] + bv[ni] + lora;
      }
    }
  }
#undef STAGE64
}

// ---------------- host launcher ----------------
extern "C" void kernel_launch(void* const* d_in, const int* in_sizes, int n_in,
                              void* d_out, int out_size, void* d_ws, size_t ws_size,
                              hipStream_t stream) {
  const float* x     = (const float*)d_in[0];  // [8,2048,4096]
  const float* w     = (const float*)d_in[1];  // [4096,4096]
  const float* bias  = (const float*)d_in[2];  // [4096]
  const float* loraA = (const float*)d_in[3];  // [32,4096,16]
  const float* loraB = (const float*)d_in[4];  // [32,16,4096]
  const int*   idx   = (const int*)d_in[5];    // [8]
  float* out = (float*)d_out;

  char* ws = (char*)d_ws;
  unsigned short* xb   = (unsigned short*)ws;                  // 134,217,728 B
  unsigned short* wbuf = (unsigned short*)(ws + 134217728);    //  33,554,432 B
  float* inter = (float*)(ws + 134217728 + 33554432);          //   1,048,576 B

  cvt_bf16_kernel<<<2048, 256, 0, stream>>>(x, xb, M_TOT * K_TOT / 4);
  cvt_bf16_kernel<<<1024, 256, 0, stream>>>(w, wbuf, N_TOT * K_TOT / 4);
  lora_inter_mfma_kernel<<<M_TOT / 64, 256, 0, stream>>>(xb, loraA, idx, inter);
  gemm_fused_kernel<<<(M_TOT / 256) * (N_TOT / 256), 512, 0, stream>>>(
      xb, wbuf, bias, inter, loraB, idx, out);
}

// Round 17
// 718.900 us; speedup vs baseline: 1.0033x; 1.0033x over previous
//
#include <hip/hip_runtime.h>
#include <hip/hip_bf16.h>

// MultiLoRALinear: out = x@W.T + bias + (x @ A[idx]) @ B[idx]
// M=16384, K=4096, N=4096, rank 16.
//
// R17 = R16 (32x32x16 MFMA, BK=64 dbuf-2) with the bank-conflict fix.
// R16 evidence: 5.03e7 conflicts = +4.0 cyc/read. Cause: slot didn't depend
// on lane bit 4 -> lanes l and l+16 hit identical banks (DS phase pairing);
// R15's conflict-free pattern had slot ^= (lane>>4). Fix: phys_slot =
// s ^ (row&7) ^ (((row>>4)&1)<<2), applied on BOTH staging source and reads.
// Invariance audit: staging row=tid>>3 (+64i: both terms invariant); reads
// mi*32/ni*32/wc*64 all even in row-bit-4 -> (rowl>>4)&1 suffices.

#define M_TOT 16384
#define K_TOT 4096
#define N_TOT 4096
#define RANK 16
#define NT2 64   // K_TOT / 64

typedef __attribute__((ext_vector_type(8))) short bf16x8;
typedef __attribute__((ext_vector_type(4))) float f32x4;
typedef __attribute__((ext_vector_type(16))) float f32x16;

// ---------------- fp32 -> bf16 (round-to-nearest-even) ----------------
__device__ __forceinline__ unsigned short f2bf(float f) {
  unsigned int u = __builtin_bit_cast(unsigned int, f);
  u += 0x7fffu + ((u >> 16) & 1u);
  return (unsigned short)(u >> 16);
}

__global__ void cvt_bf16_kernel(const float* __restrict__ src,
                                unsigned short* __restrict__ dst, int n4) {
  int i = blockIdx.x * blockDim.x + threadIdx.x;
  const int stride = gridDim.x * blockDim.x;
  for (; i < n4; i += stride) {
    const float4 v = reinterpret_cast<const float4*>(src)[i];
    ushort4 o;
    o.x = f2bf(v.x); o.y = f2bf(v.y); o.z = f2bf(v.z); o.w = f2bf(v.w);
    reinterpret_cast<ushort4*>(dst)[i] = o;
  }
}

// ------------- inter = x @ A[slot] via MFMA (wave: 16 rows x r16) -------------
__global__ __launch_bounds__(256) void lora_inter_mfma_kernel(
    const unsigned short* __restrict__ xb,
    const float* __restrict__ loraA,
    const int* __restrict__ idx,
    float* __restrict__ inter) {
  const int lane = threadIdx.x & 63;
  const int wv = threadIdx.x >> 6;
  const int m0 = blockIdx.x * 64 + wv * 16;
  const int slot = idx[m0 >> 11];
  const int q = lane >> 4;
  const int c = lane & 15;
  const unsigned short* __restrict__ xrow = xb + (size_t)(m0 + c) * K_TOT + q * 8;
  const float* __restrict__ Abase = loraA + (size_t)slot * K_TOT * RANK + c;

  f32x4 acc = (f32x4){0.f, 0.f, 0.f, 0.f};
#pragma unroll 4
  for (int kt = 0; kt < K_TOT; kt += 32) {
    const bf16x8 af = *reinterpret_cast<const bf16x8*>(xrow + kt);
    const float* __restrict__ Ak = Abase + (size_t)(kt + q * 8) * RANK;
    bf16x8 bfr;
#pragma unroll
    for (int j = 0; j < 8; ++j) bfr[j] = (short)f2bf(Ak[(size_t)j * RANK]);
    acc = __builtin_amdgcn_mfma_f32_16x16x32_bf16(af, bfr, acc, 0, 0, 0);
  }
#pragma unroll
  for (int i = 0; i < 4; ++i)
    inter[(size_t)(m0 + q * 4 + i) * RANK + c] = acc[i];
}

// ---------------- BK=64 dbuf-2 256x256 GEMM, 8 waves, 32x32x16 ----------------
__device__ __forceinline__ void gload16(const void* g, void* l) {
  __builtin_amdgcn_global_load_lds(
      (const __attribute__((address_space(1))) unsigned int*)g,
      (__attribute__((address_space(3))) unsigned int*)l, 16, 0, 0);
}

#define GBARRIER() asm volatile("s_barrier" ::: "memory")
#define RD(p) (*reinterpret_cast<const bf16x8*>(p))

__global__ __launch_bounds__(512, 2) void gemm_fused_kernel(
    const unsigned short* __restrict__ xb,   // [M][K] bf16
    const unsigned short* __restrict__ wb,   // [N][K] bf16
    const float* __restrict__ bias,          // [N]
    const float* __restrict__ inter,         // [M][RANK] f32
    const float* __restrict__ loraB,         // [32][RANK][N] f32
    const int* __restrict__ idx,             // [8]
    float* __restrict__ out) {               // [M][N] f32
  // dbuf-2 x (A: 256x64 bf16 = 32KB @0, B: 32KB @32768) = 128 KiB
  __shared__ unsigned short lds[2][32768];
  char* ldsB = (char*)&lds[0][0];

  const int tid = threadIdx.x;
  const int lane = tid & 63;
  const int wv = tid >> 6;   // 0..7
  const int wr = wv >> 2;    // 0..1 (M half)
  const int wc = wv & 3;     // 0..3 (N quarter)

  // XCD-aware bijective swizzle: 1024 wgs, 8 XCDs, 128 per chunk
  const int bid = ((blockIdx.x & 7) << 7) | (blockIdx.x >> 3);
  const int m0 = (bid >> 4) << 8;   // 64 M-panels
  const int n0 = (bid & 15) << 8;   // 16 N-panels

  // ---- staging source (pre-permuted; slot = s ^ (row&7) ^ ((row>>4)&1)<<2) ----
  const int r0 = tid >> 3;                              // 0..63
  const int scol = ((tid & 7) ^ (r0 & 7) ^ (((r0 >> 4) & 1) << 2)) << 3;
  const unsigned short* xsrc = xb + (size_t)(m0 + r0) * K_TOT + scol;
  const unsigned short* wsrc = wb + (size_t)(n0 + r0) * K_TOT + scol;
  const int stg = tid << 4;

#define STAGE64(t)                                                       \
  do {                                                                   \
    const int _bo = (((t) & 1) << 16);                                   \
    const size_t _ko = (size_t)(t) * 64;                                 \
    gload16(xsrc + _ko,                        ldsB + _bo + stg);        \
    gload16(xsrc + (size_t)64  * K_TOT + _ko,  ldsB + _bo + 8192 + stg); \
    gload16(xsrc + (size_t)128 * K_TOT + _ko,  ldsB + _bo + 16384 + stg);\
    gload16(xsrc + (size_t)192 * K_TOT + _ko,  ldsB + _bo + 24576 + stg);\
    gload16(wsrc + _ko,                        ldsB + _bo + 32768 + stg);\
    gload16(wsrc + (size_t)64  * K_TOT + _ko,  ldsB + _bo + 40960 + stg);\
    gload16(wsrc + (size_t)128 * K_TOT + _ko,  ldsB + _bo + 49152 + stg);\
    gload16(wsrc + (size_t)192 * K_TOT + _ko,  ldsB + _bo + 57344 + stg);\
  } while (0)

  // ---- ds_read bases: row=l&31, slot=(kk<<1)|h ^ (row&7) ^ ((row>>4)&1)<<2 ----
  const int rowl = lane & 31;
  const int hc = (((lane >> 5) ^ (lane & 7) ^ (((lane >> 4) & 1) << 2)) << 4);
  const int abase = (wr * 128 + rowl) * 128 + hc;           // + mi*4096 ^ kk<<5
  const int bbase = 32768 + (wc * 64 + rowl) * 128 + hc;    // + ni*4096 ^ kk<<5

  f32x16 acc[4][2];
#pragma unroll
  for (int i = 0; i < 4; ++i)
#pragma unroll
    for (int j = 0; j < 2; ++j)
#pragma unroll
      for (int e = 0; e < 16; ++e) acc[i][j][e] = 0.f;

  // ---- prologue: stage tile 0, drain, barrier ----
  STAGE64(0);
  asm volatile("s_waitcnt vmcnt(0)" ::: "memory");
  GBARRIER();

#pragma unroll 1
  for (int t = 0; t < NT2; ++t) {
    const char* base = ldsB + ((t & 1) << 16);
    bf16x8 af[8], bf0[4], bf1[4];

    // cluster-1 reads (kk 0,1): B 4 + A 8; plus cluster-2 B reads (kk 2,3)
#pragma unroll
    for (int ni = 0; ni < 2; ++ni)
#pragma unroll
      for (int kk = 0; kk < 2; ++kk)
        bf0[ni * 2 + kk] = RD(base + ((bbase + ni * 4096) ^ (kk << 5)));
#pragma unroll
    for (int mi = 0; mi < 4; ++mi)
#pragma unroll
      for (int kk = 0; kk < 2; ++kk)
        af[mi * 2 + kk] = RD(base + ((abase + mi * 4096) ^ (kk << 5)));
#pragma unroll
    for (int ni = 0; ni < 2; ++ni)
#pragma unroll
      for (int kk = 0; kk < 2; ++kk)
        bf1[ni * 2 + kk] = RD(base + ((bbase + ni * 4096) ^ ((2 + kk) << 5)));
    if (t < NT2 - 1) STAGE64(t + 1);

    // wait cluster-1's 12 reads; bf1's 4 stay in flight under MFMA-1
    asm volatile("s_waitcnt lgkmcnt(4)" ::: "memory");
    __builtin_amdgcn_sched_barrier(0);
    __builtin_amdgcn_s_setprio(1);
#pragma unroll
    for (int mi = 0; mi < 4; ++mi)
#pragma unroll
      for (int ni = 0; ni < 2; ++ni)
#pragma unroll
        for (int kk = 0; kk < 2; ++kk)
          acc[mi][ni] = __builtin_amdgcn_mfma_f32_32x32x16_bf16(
              af[mi * 2 + kk], bf0[ni * 2 + kk], acc[mi][ni], 0, 0, 0);
    __builtin_amdgcn_s_setprio(0);
    __builtin_amdgcn_sched_barrier(0);  // pin: cluster-2 A reads stay below

    // cluster-2 A reads (kk 2,3), reuse af
#pragma unroll
    for (int mi = 0; mi < 4; ++mi)
#pragma unroll
      for (int kk = 0; kk < 2; ++kk)
        af[mi * 2 + kk] = RD(base + ((abase + mi * 4096) ^ ((2 + kk) << 5)));
    asm volatile("s_waitcnt lgkmcnt(0)" ::: "memory");
    __builtin_amdgcn_sched_barrier(0);
    __builtin_amdgcn_s_setprio(1);
#pragma unroll
    for (int mi = 0; mi < 4; ++mi)
#pragma unroll
      for (int ni = 0; ni < 2; ++ni)
#pragma unroll
        for (int kk = 0; kk < 2; ++kk)
          acc[mi][ni] = __builtin_amdgcn_mfma_f32_32x32x16_bf16(
              af[mi * 2 + kk], bf1[ni * 2 + kk], acc[mi][ni], 0, 0, 0);
    __builtin_amdgcn_s_setprio(0);
    __builtin_amdgcn_sched_barrier(0);

    // boundary: stage(t+1) resident for all waves
    asm volatile("s_waitcnt vmcnt(0)" ::: "memory");
    GBARRIER();
  }

  // ---- epilogue: out = acc + bias + inter @ B[slot] (32x32 C/D map) ----
  // col = lane&31; row = (r&3) + 8*(r>>2) + 4*(lane>>5)
  const int slot = idx[m0 >> 11];
  const float* __restrict__ Bmat = loraB + (size_t)slot * RANK * N_TOT;
  const int halfsel = (lane >> 5) << 2;
  const int gn0 = n0 + wc * 64 + rowl;

  float bcv[2][RANK];
  float bv[2];
#pragma unroll
  for (int ni = 0; ni < 2; ++ni) {
    const int gn = gn0 + ni * 32;
    bv[ni] = bias[gn];
#pragma unroll
    for (int p = 0; p < RANK; ++p) bcv[ni][p] = Bmat[(size_t)p * N_TOT + gn];
  }
#pragma unroll
  for (int mi = 0; mi < 4; ++mi) {
#pragma unroll
    for (int r = 0; r < 16; ++r) {
      const int gm = m0 + wr * 128 + mi * 32 + (r & 3) + 8 * (r >> 2) + halfsel;
      const float4* ivp = reinterpret_cast<const float4*>(inter + (size_t)gm * RANK);
      const float4 iv0 = ivp[0], iv1 = ivp[1], iv2 = ivp[2], iv3 = ivp[3];
      float* orow = out + (size_t)gm * N_TOT;
#pragma unroll
      for (int ni = 0; ni < 2; ++ni) {
        const float lora =
            iv0.x * bcv[ni][0]  + iv0.y * bcv[ni][1]  + iv0.z * bcv[ni][2]  + iv0.w * bcv[ni][3] +
            iv1.x * bcv[ni][4]  + iv1.y * bcv[ni][5]  + iv1.z * bcv[ni][6]  + iv1.w * bcv[ni][7] +
            iv2.x * bcv[ni][8]  + iv2.y * bcv[ni][9]  + iv2.z * bcv[ni][10] + iv2.w * bcv[ni][11] +
            iv3.x * bcv[ni][12] + iv3.y * bcv[ni][13] + iv3.z * bcv[ni][14] + iv3.w * bcv[ni][15];
        orow[gn0 + ni * 32] = acc[mi][ni][r] + bv[ni] + lora;
      }
    }
  }
#undef STAGE64
}

// ---------------- host launcher ----------------
extern "C" void kernel_launch(void* const* d_in, const int* in_sizes, int n_in,
                              void* d_out, int out_size, void* d_ws, size_t ws_size,
                              hipStream_t stream) {
  const float* x     = (const float*)d_in[0];  // [8,2048,4096]
  const float* w     = (const float*)d_in[1];  // [4096,4096]
  const float* bias  = (const float*)d_in[2];  // [4096]
  const float* loraA = (const float*)d_in[3];  // [32,4096,16]
  const float* loraB = (const float*)d_in[4];  // [32,16,4096]
  const int*   idx   = (const int*)d_in[5];    // [8]
  float* out = (float*)d_out;

  char* ws = (char*)d_ws;
  unsigned short* xb   = (unsigned short*)ws;                  // 134,217,728 B
  unsigned short* wbuf = (unsigned short*)(ws + 134217728);    //  33,554,432 B
  float* inter = (float*)(ws + 134217728 + 33554432);          //   1,048,576 B

  cvt_bf16_kernel<<<2048, 256, 0, stream>>>(x, xb, M_TOT * K_TOT / 4);
  cvt_bf16_kernel<<<1024, 256, 0, stream>>>(w, wbuf, N_TOT * K_TOT / 4);
  lora_inter_mfma_kernel<<<M_TOT / 64, 256, 0, stream>>>(xb, loraA, idx, inter);
  gemm_fused_kernel<<<(M_TOT / 256) * (N_TOT / 256), 512, 0, stream>>>(
      xb, wbuf, bias, inter, loraB, idx, out);
}